// Round 4
// baseline (207.208 us; speedup 1.0000x reference)
//
#include <hip/hip_runtime.h>
#include <math.h>

// Problem constants (B, N, D2, S = 64, 4096, 128, 512)
#define BB 64
#define NN 4096
#define DD 128
#define SS 512
#define CH2 32    // chunks per b
#define RPC2 128  // rows per chunk = NN / CH2

// ---------------------------------------------------------------------------
// Kernel 1: q[b,e] = sum_d yq[b,d] * w[d,e]   (tiny GEMV, 64x128 out)
// ---------------------------------------------------------------------------
__global__ void compute_q_kernel(const float* __restrict__ yq,
                                 const float* __restrict__ w,
                                 float* __restrict__ q) {
    int b = blockIdx.x;
    int e = threadIdx.x;  // 0..127
    __shared__ float syq[DD];
    syq[e] = yq[b * DD + e];
    __syncthreads();
    float acc = 0.f;
#pragma unroll
    for (int d = 0; d < DD; ++d) acc = fmaf(syq[d], w[d * DD + e], acc);
    q[b * DD + e] = acc;
}

// ---------------------------------------------------------------------------
// Fused kernel, register-direct (no LDS staging, no barriers in stream loop).
// grid (BB, CH2), block 256. Each block: 128 rows.
// Lane mapping: g = t&7 (eighth of row), rg = t>>3 (row group 0..31).
// Per wave-instr: 8 rows x 8 contiguous float4 = 8 x 128B segments (coalesced).
// 16 independent float4 loads per lane -> deep memory pipelining.
// Reduce: 3 shuffles per 4 rows; chunk max; exp; LDS bins[512]; write bins+max.
// ---------------------------------------------------------------------------
__global__ __launch_bounds__(256) void fused_kernel(
    const float* __restrict__ y_past, const float* __restrict__ q,
    const int* __restrict__ s_past, float* __restrict__ bins_g,
    float* __restrict__ pmax) {
    int b = blockIdx.x, chunk = blockIdx.y;
    int t = threadIdx.x;

    __shared__ float bins[SS];
    __shared__ float qsh[DD];
    __shared__ int ssh[RPC2];
    __shared__ float wred[4];
    __shared__ float s_m;

    bins[t] = 0.f;
    bins[t + 256] = 0.f;
    if (t < DD) qsh[t] = q[b * DD + t];
    if (t < RPC2) ssh[t] = s_past[b * NN + chunk * RPC2 + t];
    __syncthreads();

    int g = t & 7;    // lane within row group (eighth of a 128-float row)
    int rg = t >> 3;  // row group id within block (0..31)

    float4 qreg[4];
#pragma unroll
    for (int k = 0; k < 4; ++k) qreg[k] = ((const float4*)qsh)[g + 8 * k];

    const float4* gp =
        (const float4*)y_past + ((size_t)b * NN + (size_t)chunk * RPC2) * 32;

    float pv[4];
#pragma unroll
    for (int s = 0; s < 4; ++s) {
        int row = s * 32 + rg;
        const float4* rp = gp + (size_t)row * 32 + g;
        float4 a0 = rp[0], a1 = rp[8], a2 = rp[16], a3 = rp[24];
        float acc = 0.f;
        acc = fmaf(qreg[0].x, a0.x, acc);
        acc = fmaf(qreg[0].y, a0.y, acc);
        acc = fmaf(qreg[0].z, a0.z, acc);
        acc = fmaf(qreg[0].w, a0.w, acc);
        acc = fmaf(qreg[1].x, a1.x, acc);
        acc = fmaf(qreg[1].y, a1.y, acc);
        acc = fmaf(qreg[1].z, a1.z, acc);
        acc = fmaf(qreg[1].w, a1.w, acc);
        acc = fmaf(qreg[2].x, a2.x, acc);
        acc = fmaf(qreg[2].y, a2.y, acc);
        acc = fmaf(qreg[2].z, a2.z, acc);
        acc = fmaf(qreg[2].w, a2.w, acc);
        acc = fmaf(qreg[3].x, a3.x, acc);
        acc = fmaf(qreg[3].y, a3.y, acc);
        acc = fmaf(qreg[3].z, a3.z, acc);
        acc = fmaf(qreg[3].w, a3.w, acc);
        // reduce across the 8 lanes of the row group (xor 1,2,4 stay in-group)
        acc += __shfl_xor(acc, 1, 64);
        acc += __shfl_xor(acc, 2, 64);
        acc += __shfl_xor(acc, 4, 64);
        pv[s] = acc;  // all 8 lanes of the group hold the full row dot
    }

    // ---- chunk max over this block's 128 rows ----
    float m = fmaxf(fmaxf(pv[0], pv[1]), fmaxf(pv[2], pv[3]));
    m = fmaxf(m, __shfl_xor(m, 8, 64));
    m = fmaxf(m, __shfl_xor(m, 16, 64));
    m = fmaxf(m, __shfl_xor(m, 32, 64));
    int wave = t >> 6, lane = t & 63;
    if (lane == 0) wred[wave] = m;
    __syncthreads();
    if (t == 0)
        s_m = fmaxf(fmaxf(wred[0], wred[1]), fmaxf(wred[2], wred[3]));
    __syncthreads();
    m = s_m;

    // ---- scatter exp(p - m_c) into LDS bins (one lane per row) ----
    if (g == 0) {
#pragma unroll
        for (int s = 0; s < 4; ++s)
            atomicAdd(&bins[ssh[s * 32 + rg]], __expf(pv[s] - m));
    }
    __syncthreads();

    // ---- write chunk bins + max; s_c = sum(bins) recovered in combine ----
    float* bg = bins_g + ((size_t)b * CH2 + chunk) * SS;
    bg[t] = bins[t];
    bg[t + 256] = bins[t + 256];
    if (t == 0) pmax[b * CH2 + chunk] = m;
}

// ---------------------------------------------------------------------------
// Combine: out[b,s] = (sum_c bins[b,c,s] * exp(m_c - M)) / S,
// S recovered as block-wide sum of numerators. 64 blocks x 512 thr.
// ---------------------------------------------------------------------------
__global__ __launch_bounds__(512) void combine_kernel(
    const float* __restrict__ bins_g, const float* __restrict__ pmax,
    float* __restrict__ out) {
    int b = blockIdx.x;
    int t = threadIdx.x;  // 0..511
    __shared__ float scale[CH2];
    __shared__ float red[8];
    __shared__ float sInv;

    if (t < CH2) scale[t] = pmax[b * CH2 + t];
    __syncthreads();
    if (t == 0) {
        float M = scale[0];
#pragma unroll
        for (int c = 1; c < CH2; ++c) M = fmaxf(M, scale[c]);
#pragma unroll
        for (int c = 0; c < CH2; ++c) scale[c] = __expf(scale[c] - M);
    }
    __syncthreads();

    float acc = 0.f;
#pragma unroll
    for (int c = 0; c < CH2; ++c)
        acc = fmaf(bins_g[((size_t)b * CH2 + c) * SS + t], scale[c], acc);

    float s = acc;
#pragma unroll
    for (int off = 32; off > 0; off >>= 1) s += __shfl_xor(s, off, 64);
    if ((t & 63) == 0) red[t >> 6] = s;
    __syncthreads();
    if (t == 0) {
        float S = 0.f;
#pragma unroll
        for (int i = 0; i < 8; ++i) S += red[i];
        sInv = 1.f / S;
    }
    __syncthreads();

    out[b * SS + t] = acc * sInv;
}

// ---------------------------------------------------------------------------
// Launch. Inputs: [0]=s_past(int B*N), [1]=yq(f32 B*D2), [2]=y_past(f32
// B*N*D2), [3]=w_mat(f32 D2*D2), [4]=size_s. Out: post_est f32 B*S.
// ws: q (8192) | bins_g (B*CH2*S = 4 MB) | pmax (B*CH2)
// ---------------------------------------------------------------------------
extern "C" void kernel_launch(void* const* d_in, const int* in_sizes, int n_in,
                              void* d_out, int out_size, void* d_ws, size_t ws_size,
                              hipStream_t stream) {
    const int*   s_past = (const int*)d_in[0];
    const float* yq     = (const float*)d_in[1];
    const float* y_past = (const float*)d_in[2];
    const float* w_mat  = (const float*)d_in[3];

    float* ws     = (float*)d_ws;
    float* q      = ws;                       // BB*DD
    float* bins_g = q + BB * DD;              // BB*CH2*SS
    float* pmax   = bins_g + BB * CH2 * SS;   // BB*CH2
    float* out    = (float*)d_out;

    compute_q_kernel<<<BB, DD, 0, stream>>>(yq, w_mat, q);
    fused_kernel<<<dim3(BB, CH2), 256, 0, stream>>>(y_past, q, s_past, bins_g,
                                                    pmax);
    combine_kernel<<<BB, SS, 0, stream>>>(bins_g, pmax, out);
}